// Round 2
// baseline (882.225 us; speedup 1.0000x reference)
//
#include <hip/hip_runtime.h>
#include <math.h>

// Problem constants (from reference setup_inputs)
#define BB 64
#define MM 50
#define PP 24564
#define CC 2
#define NBLK ((PP + 255) / 256)   // 96 blocks of 256 over priors
#define THRESH 0.2f
#define P4 (PP / 4)               // 6141 float4s, exact

// ---------------- kernel 0: priors cxcy -> xy + area, and zero ghist ----------------
__global__ void k_priors(const float4* __restrict__ pr_cxcy,
                         float4* __restrict__ pr_xy,
                         float* __restrict__ parea,
                         int* __restrict__ ghist) {
    int p = blockIdx.x * 256 + threadIdx.x;
    // zero the per-image top11 histograms (64 * 2048 ints)
    for (int i = p; i < BB * 2048; i += NBLK * 256) ghist[i] = 0;
    if (p >= PP) return;
    float4 c = pr_cxcy[p];
    float4 xy;
    xy.x = c.x - c.z * 0.5f;
    xy.y = c.y - c.w * 0.5f;
    xy.z = c.x + c.z * 0.5f;
    xy.w = c.y + c.w * 0.5f;
    pr_xy[p] = xy;
    parea[p] = (xy.z - xy.x) * (xy.w - xy.y);
}

__device__ __forceinline__ float iou_fn(float4 a, float area_a, float4 b, float area_b) {
    float lx = fmaxf(a.x, b.x), ly = fmaxf(a.y, b.y);
    float rx = fminf(a.z, b.z), ry = fminf(a.w, b.w);
    float iw = fmaxf(rx - lx, 0.0f), ih = fmaxf(ry - ly, 0.0f);
    float inter = iw * ih;
    return inter / (area_a + area_b - inter);
}

// ---------------- kernel A: per-prior best object (max/argmax over M) ----------------
__global__ void k_best_per_prior(const float4* __restrict__ pr_xy,
                                 const float* __restrict__ parea,
                                 const float4* __restrict__ boxes,
                                 float* __restrict__ ovbest,
                                 int* __restrict__ objbest) {
    int b = blockIdx.y;
    int p = blockIdx.x * 256 + threadIdx.x;
    __shared__ float4 sbox[MM];
    __shared__ float sarea[MM];
    if (threadIdx.x < MM) {
        float4 bx = boxes[b * MM + threadIdx.x];
        sbox[threadIdx.x] = bx;
        sarea[threadIdx.x] = (bx.z - bx.x) * (bx.w - bx.y);
    }
    __syncthreads();
    if (p >= PP) return;
    float4 pxy = pr_xy[p];
    float pa = parea[p];
    float best = -1.0f;
    int bm = 0;
    for (int m = 0; m < MM; ++m) {
        float iou = iou_fn(sbox[m], sarea[m], pxy, pa);
        if (iou > best) { best = iou; bm = m; }   // strict > : first occurrence wins
    }
    ovbest[(size_t)b * PP + p] = best;
    objbest[(size_t)b * PP + p] = bm;
}

// ---------------- kernel B: per-object best prior (argmax over P) ----------------
__global__ void k_best_per_object(const float4* __restrict__ pr_xy,
                                  const float* __restrict__ parea,
                                  const float4* __restrict__ boxes,
                                  int* __restrict__ pfeo) {
    int m = blockIdx.x, b = blockIdx.y;
    float4 bx = boxes[b * MM + m];
    float ba = (bx.z - bx.x) * (bx.w - bx.y);
    unsigned long long bestkey = 0ull;
    for (int p = threadIdx.x; p < PP; p += 256) {
        float iou = iou_fn(bx, ba, pr_xy[p], parea[p]);
        unsigned long long key =
            ((unsigned long long)__float_as_uint(iou) << 32) | (unsigned int)(~p);
        if (key > bestkey) bestkey = key;
    }
    __shared__ unsigned long long sk[256];
    sk[threadIdx.x] = bestkey;
    __syncthreads();
    for (int s = 128; s > 0; s >>= 1) {
        if (threadIdx.x < s) {
            unsigned long long o = sk[threadIdx.x + s];
            if (o > sk[threadIdx.x]) sk[threadIdx.x] = o;
        }
        __syncthreads();
    }
    if (threadIdx.x == 0) pfeo[b * MM + m] = (int)(~(unsigned int)sk[0]);
}

// ---------------- kernel C: force-assign (sequential per image) ----------------
__global__ void k_force(const int* __restrict__ pfeo,
                        float* __restrict__ ovbest,
                        int* __restrict__ objbest) {
    int b = threadIdx.x;
    if (b >= BB) return;
    for (int m = 0; m < MM; ++m) {          // ascending m: last-wins on duplicates
        int p = pfeo[b * MM + m];
        objbest[(size_t)b * PP + p] = m;
        ovbest[(size_t)b * PP + p] = 1.0f;
    }
}

// ---------------- kernel D: per-prior loss terms + partials + top11 histogram ----------------
__global__ void k_perprior(const float* __restrict__ ovbest,
                           const int* __restrict__ objbest,
                           const float4* __restrict__ boxes,
                           const float4* __restrict__ pr_cxcy,
                           const float4* __restrict__ plocs,
                           const float2* __restrict__ scores,
                           float* __restrict__ confneg,
                           int* __restrict__ ghist,
                           int* __restrict__ npos_part,
                           float* __restrict__ cpos_part,
                           float* __restrict__ loc_part) {
    int b = blockIdx.y;
    int p = blockIdx.x * 256 + threadIdx.x;
    int np = 0;
    float cpos = 0.0f, lloc = 0.0f;
    if (p < PP) {
        size_t idx = (size_t)b * PP + p;
        float ov = ovbest[idx];
        bool pos = (ov >= THRESH);
        float2 sc = scores[idx];
        float mx = fmaxf(sc.x, sc.y);
        float lse = mx + logf(expf(sc.x - mx) + expf(sc.y - mx));
        float conf = pos ? (lse - sc.y) : (lse - sc.x);   // -logp[label]
        float key = pos ? 0.0f : conf;
        confneg[idx] = key;
        atomicAdd(&ghist[b * 2048 + (__float_as_uint(key) >> 20)], 1);
        if (pos) {
            np = 1;
            cpos = conf;
            int obj = objbest[idx];
            float4 bx = boxes[b * MM + obj];
            float cx = (bx.x + bx.z) * 0.5f, cy = (bx.y + bx.w) * 0.5f;
            float w = bx.z - bx.x, h = bx.w - bx.y;
            float4 pc = pr_cxcy[p];
            float g0 = (cx - pc.x) / (pc.z * 0.1f);
            float g1 = (cy - pc.y) / (pc.w * 0.1f);
            float g2 = logf(w / pc.z) * 5.0f;
            float g3 = logf(h / pc.w) * 5.0f;
            float4 pl = plocs[idx];
            lloc = fabsf(pl.x - g0) + fabsf(pl.y - g1) +
                   fabsf(pl.z - g2) + fabsf(pl.w - g3);
        }
    }
    __shared__ int si[256];
    __shared__ float s1[256], s2[256];
    si[threadIdx.x] = np; s1[threadIdx.x] = cpos; s2[threadIdx.x] = lloc;
    __syncthreads();
    for (int s = 128; s > 0; s >>= 1) {
        if (threadIdx.x < s) {
            si[threadIdx.x] += si[threadIdx.x + s];
            s1[threadIdx.x] += s1[threadIdx.x + s];
            s2[threadIdx.x] += s2[threadIdx.x + s];
        }
        __syncthreads();
    }
    if (threadIdx.x == 0) {
        int o = b * NBLK + blockIdx.x;
        npos_part[o] = si[0];
        cpos_part[o] = s1[0];
        loc_part[o] = s2[0];
    }
}

// ---------------- kernel E: per-image exact top-K sum via 3-level radix select ----------------
__device__ __forceinline__ float block_sum(float v, float* fred, int tid) {
    fred[tid] = v;
    __syncthreads();
    for (int s = 128; s > 0; s >>= 1) {
        if (tid < s) fred[tid] += fred[tid + s];
        __syncthreads();
    }
    float r = fred[0];
    __syncthreads();
    return r;
}

__global__ void k_select(const float* __restrict__ confneg,
                         const int* __restrict__ ghist,
                         const int* __restrict__ npos_part,
                         float* __restrict__ chard) {
    int b = blockIdx.x, tid = threadIdx.x;
    __shared__ int h[2048];
    __shared__ float store[2048];
    __shared__ float fred[256];
    __shared__ int ired[256];
    __shared__ int bc[8];

    // reduce this image's n_pos partials
    ired[tid] = (tid < NBLK) ? npos_part[b * NBLK + tid] : 0;
    __syncthreads();
    for (int s = 128; s > 0; s >>= 1) {
        if (tid < s) ired[tid] += ired[tid + s];
        __syncthreads();
    }
    int npos = ired[0];
    long long Kl = 3LL * npos;
    int K = (Kl > PP) ? PP : (int)Kl;
    if (K == 0) {
        if (tid == 0) chard[b] = 0.0f;
        return;
    }

    // level 1: top 11 bits, histogram prebuilt in k_perprior
    for (int i = tid; i < 2048; i += 256) h[i] = ghist[b * 2048 + i];
    __syncthreads();
    if (tid == 0) {
        int acc = 0, b1 = 0, cg = 0;
        for (int i = 2047; i >= 0; --i) {
            acc += h[i];
            if (acc >= K) { b1 = i; cg = acc - h[i]; break; }
        }
        bc[0] = b1; bc[1] = K - cg;     // K1: rank within bucket b1
    }
    __syncthreads();
    int b1 = bc[0], K1 = bc[1];

    // pass A: S_a (sum of strictly-higher buckets) + hist2 of next-10 bits in b1
    for (int i = tid; i < 1024; i += 256) h[i] = 0;
    __syncthreads();
    const float4* cn4 = (const float4*)(confneg + (size_t)b * PP);
    float sa = 0.0f;
    for (int i = tid; i < P4; i += 256) {
        float4 q = cn4[i];
        float vv[4] = {q.x, q.y, q.z, q.w};
        #pragma unroll
        for (int j = 0; j < 4; ++j) {
            unsigned k = __float_as_uint(vv[j]);
            int t11 = (int)(k >> 20);
            if (t11 > b1) sa += vv[j];
            else if (t11 == b1) atomicAdd(&h[(k >> 10) & 1023], 1);
        }
    }
    float Sa = block_sum(sa, fred, tid);
    if (tid == 0) {
        int acc = 0, b2 = 0, cg = 0;
        for (int i = 1023; i >= 0; --i) {
            acc += h[i];
            if (acc >= K1) { b2 = i; cg = acc - h[i]; break; }
        }
        bc[2] = b2; bc[3] = K1 - cg; bc[4] = h[b2];   // K2, count in (b1,b2)
    }
    __syncthreads();
    int b2 = bc[2], K2 = bc[3], h2cnt = bc[4];
    bool collect = (h2cnt <= 2048);

    // pass B: S_b + hist3 of low-10 bits in (b1,b2); collect bucket values
    for (int i = tid; i < 1024; i += 256) h[i] = 0;
    if (tid == 0) bc[5] = 0;
    __syncthreads();
    unsigned top21 = ((unsigned)b1 << 10) | (unsigned)b2;
    float sb = 0.0f;
    for (int i = tid; i < P4; i += 256) {
        float4 q = cn4[i];
        float vv[4] = {q.x, q.y, q.z, q.w};
        #pragma unroll
        for (int j = 0; j < 4; ++j) {
            unsigned k = __float_as_uint(vv[j]);
            if ((int)(k >> 20) == b1) {
                int n10 = (int)((k >> 10) & 1023);
                if (n10 > b2) sb += vv[j];
                else if (n10 == b2) {
                    atomicAdd(&h[k & 1023], 1);
                    if (collect) {
                        int ix = atomicAdd(&bc[5], 1);
                        if (ix < 2048) store[ix] = vv[j];
                    }
                }
            }
        }
    }
    float Sb = block_sum(sb, fred, tid);
    if (tid == 0) {
        int acc = 0, b3 = 0, cg = 0;
        for (int i = 1023; i >= 0; --i) {
            acc += h[i];
            if (acc >= K2) { b3 = i; cg = acc - h[i]; break; }
        }
        bc[6] = b3; bc[7] = K2 - cg;    // K3 = number of ties to take
    }
    __syncthreads();
    int b3 = bc[6], K3 = bc[7];
    unsigned kstar = (top21 << 10) | (unsigned)b3;
    float kval = __uint_as_float(kstar);

    // S_c: sum of values in bucket (b1,b2) strictly above kstar
    float sc = 0.0f;
    if (collect) {
        for (int i = tid; i < h2cnt; i += 256)
            if (__float_as_uint(store[i]) > kstar) sc += store[i];
    } else {
        for (int i = tid; i < P4; i += 256) {
            float4 q = cn4[i];
            float vv[4] = {q.x, q.y, q.z, q.w};
            #pragma unroll
            for (int j = 0; j < 4; ++j) {
                unsigned k = __float_as_uint(vv[j]);
                if ((k >> 10) == top21 && (k & 1023) > (unsigned)b3) sc += vv[j];
            }
        }
    }
    float Sc = block_sum(sc, fred, tid);
    if (tid == 0) chard[b] = Sa + Sb + Sc + (float)K3 * kval;
}

// ---------------- kernel F: final deterministic combine ----------------
__global__ void k_final(const int* __restrict__ npos_part,
                        const float* __restrict__ cpos_part,
                        const float* __restrict__ loc_part,
                        const float* __restrict__ chard,
                        float* __restrict__ out) {
    __shared__ int si[256];
    __shared__ float s1[256], s2[256], s3[256];
    int tn = 0; float tc = 0.0f, tl = 0.0f;
    for (int i = threadIdx.x; i < BB * NBLK; i += 256) {
        tn += npos_part[i];
        tc += cpos_part[i];
        tl += loc_part[i];
    }
    float th = (threadIdx.x < BB) ? chard[threadIdx.x] : 0.0f;
    si[threadIdx.x] = tn; s1[threadIdx.x] = tc; s2[threadIdx.x] = tl; s3[threadIdx.x] = th;
    __syncthreads();
    for (int s = 128; s > 0; s >>= 1) {
        if (threadIdx.x < s) {
            si[threadIdx.x] += si[threadIdx.x + s];
            s1[threadIdx.x] += s1[threadIdx.x + s];
            s2[threadIdx.x] += s2[threadIdx.x + s];
            s3[threadIdx.x] += s3[threadIdx.x + s];
        }
        __syncthreads();
    }
    if (threadIdx.x == 0) {
        float tp = (float)si[0];
        out[0] = (s3[0] + s1[0]) / tp + s2[0] / (tp * 4.0f);
    }
}

extern "C" void kernel_launch(void* const* d_in, const int* in_sizes, int n_in,
                              void* d_out, int out_size, void* d_ws, size_t ws_size,
                              hipStream_t stream) {
    const float4* plocs   = (const float4*)d_in[0];   // (B,P,4)
    const float2* scores  = (const float2*)d_in[1];   // (B,P,2)
    const float4* boxes   = (const float4*)d_in[2];   // (B,M,4)
    const float4* priors  = (const float4*)d_in[3];   // (P,4) cxcywh
    float* out = (float*)d_out;

    char* ws = (char*)d_ws;
    size_t off = 0;
    auto alloc = [&](size_t bytes) -> void* {
        void* p = ws + off;
        off += (bytes + 255) & ~(size_t)255;
        return p;
    };
    float4* pr_xy    = (float4*)alloc((size_t)PP * 16);
    float*  parea    = (float*) alloc((size_t)PP * 4);
    float*  ovbest   = (float*) alloc((size_t)BB * PP * 4);
    int*    objbest  = (int*)   alloc((size_t)BB * PP * 4);
    int*    pfeo     = (int*)   alloc((size_t)BB * MM * 4);
    float*  confneg  = (float*) alloc((size_t)BB * PP * 4);
    int*    ghist    = (int*)   alloc((size_t)BB * 2048 * 4);
    int*    npos_p   = (int*)   alloc((size_t)BB * NBLK * 4);
    float*  cpos_p   = (float*) alloc((size_t)BB * NBLK * 4);
    float*  loc_p    = (float*) alloc((size_t)BB * NBLK * 4);
    float*  chard    = (float*) alloc((size_t)BB * 4);
    (void)ws_size; (void)in_sizes; (void)n_in; (void)out_size;

    k_priors<<<dim3(NBLK), 256, 0, stream>>>(priors, pr_xy, parea, ghist);
    k_best_per_prior<<<dim3(NBLK, BB), 256, 0, stream>>>(pr_xy, parea, boxes, ovbest, objbest);
    k_best_per_object<<<dim3(MM, BB), 256, 0, stream>>>(pr_xy, parea, boxes, pfeo);
    k_force<<<1, 64, 0, stream>>>(pfeo, ovbest, objbest);
    k_perprior<<<dim3(NBLK, BB), 256, 0, stream>>>(ovbest, objbest, boxes, priors,
                                                   plocs, scores, confneg, ghist,
                                                   npos_p, cpos_p, loc_p);
    k_select<<<BB, 256, 0, stream>>>(confneg, ghist, npos_p, chard);
    k_final<<<1, 256, 0, stream>>>(npos_p, cpos_p, loc_p, chard, out);
}

// Round 3
// 388.958 us; speedup vs baseline: 2.2682x; 2.2682x over previous
//
#include <hip/hip_runtime.h>
#include <math.h>

// Problem constants (from reference setup_inputs)
#define BB 64
#define MM 50
#define PP 24564
#define CC 2
#define NBLK ((PP + 255) / 256)   // 96 blocks of 256 over priors
#define THRESH 0.2f
#define P4 (PP / 4)               // 6141 float4s, exact

// ---------------- kernel 0: priors cxcy -> xy + area, and zero ghist ----------------
__global__ void k_priors(const float4* __restrict__ pr_cxcy,
                         float4* __restrict__ pr_xy,
                         float* __restrict__ parea,
                         int* __restrict__ ghist) {
    int p = blockIdx.x * 256 + threadIdx.x;
    for (int i = p; i < BB * 2048; i += NBLK * 256) ghist[i] = 0;
    if (p >= PP) return;
    float4 c = pr_cxcy[p];
    float4 xy;
    xy.x = c.x - c.z * 0.5f;
    xy.y = c.y - c.w * 0.5f;
    xy.z = c.x + c.z * 0.5f;
    xy.w = c.y + c.w * 0.5f;
    pr_xy[p] = xy;
    parea[p] = (xy.z - xy.x) * (xy.w - xy.y);
}

__device__ __forceinline__ float iou_fn(float4 a, float area_a, float4 b, float area_b) {
    float lx = fmaxf(a.x, b.x), ly = fmaxf(a.y, b.y);
    float rx = fminf(a.z, b.z), ry = fminf(a.w, b.w);
    float iw = fmaxf(rx - lx, 0.0f), ih = fmaxf(ry - ly, 0.0f);
    float inter = iw * ih;
    return inter / (area_a + area_b - inter);
}

// ---------------- kernel B: per-object best prior (argmax over P) ----------------
__global__ void k_best_per_object(const float4* __restrict__ pr_xy,
                                  const float* __restrict__ parea,
                                  const float4* __restrict__ boxes,
                                  int* __restrict__ pfeo) {
    int m = blockIdx.x, b = blockIdx.y;
    float4 bx = boxes[b * MM + m];
    float ba = (bx.z - bx.x) * (bx.w - bx.y);
    unsigned long long bestkey = 0ull;
    for (int p = threadIdx.x; p < PP; p += 256) {
        float iou = iou_fn(bx, ba, pr_xy[p], parea[p]);
        // iou >= 0 -> float bits monotone as u32; tie -> larger ~p = smaller p wins
        unsigned long long key =
            ((unsigned long long)__float_as_uint(iou) << 32) | (unsigned int)(~p);
        if (key > bestkey) bestkey = key;
    }
    __shared__ unsigned long long sk[256];
    sk[threadIdx.x] = bestkey;
    __syncthreads();
    for (int s = 128; s > 0; s >>= 1) {
        if (threadIdx.x < s) {
            unsigned long long o = sk[threadIdx.x + s];
            if (o > sk[threadIdx.x]) sk[threadIdx.x] = o;
        }
        __syncthreads();
    }
    if (threadIdx.x == 0) pfeo[b * MM + m] = (int)(~(unsigned int)sk[0]);
}

// ---------------- fused kernel: best-per-prior + force + loss terms + LDS-agg hist ----------------
__global__ void k_fused(const float4* __restrict__ pr_xy,
                        const float* __restrict__ parea,
                        const float4* __restrict__ boxes,
                        const int* __restrict__ pfeo,
                        const float4* __restrict__ pr_cxcy,
                        const float4* __restrict__ plocs,
                        const float2* __restrict__ scores,
                        float* __restrict__ confneg,
                        int* __restrict__ ghist,
                        int* __restrict__ npos_part,
                        float* __restrict__ cpos_part,
                        float* __restrict__ loc_part) {
    int b = blockIdx.y;
    int p = blockIdx.x * 256 + threadIdx.x;
    int tid = threadIdx.x;
    __shared__ float4 sbox[MM];
    __shared__ float sarea[MM];
    __shared__ int spfeo[MM];
    __shared__ int shist[2048];
    __shared__ int si[256];
    __shared__ float s1[256], s2[256];
    for (int i = tid; i < 2048; i += 256) shist[i] = 0;
    if (tid < MM) {
        float4 bx = boxes[b * MM + tid];
        sbox[tid] = bx;
        sarea[tid] = (bx.z - bx.x) * (bx.w - bx.y);
        spfeo[tid] = pfeo[b * MM + tid];
    }
    __syncthreads();

    int np = 0;
    float cpos = 0.0f, lloc = 0.0f;
    if (p < PP) {
        float4 pxy = pr_xy[p];
        float pa = parea[p];
        float best = -1.0f;
        int bm = 0;
        for (int m = 0; m < MM; ++m) {
            float iou = iou_fn(sbox[m], sarea[m], pxy, pa);
            if (iou > best) { best = iou; bm = m; }   // strict > : first occurrence wins
        }
        // force-assign: last m wins on duplicate priors (matches sequential scatter)
        for (int m = 0; m < MM; ++m) {
            if (spfeo[m] == p) { bm = m; best = 1.0f; }
        }
        bool pos = (best >= THRESH);
        size_t idx = (size_t)b * PP + p;
        float2 sc = scores[idx];
        float mx = fmaxf(sc.x, sc.y);
        float lse = mx + logf(expf(sc.x - mx) + expf(sc.y - mx));
        float conf = pos ? (lse - sc.y) : (lse - sc.x);   // -logp[label]
        float key = pos ? 0.0f : conf;
        confneg[idx] = key;
        atomicAdd(&shist[__float_as_uint(key) >> 20], 1);
        if (pos) {
            np = 1;
            cpos = conf;
            float4 bx = sbox[bm];
            float cx = (bx.x + bx.z) * 0.5f, cy = (bx.y + bx.w) * 0.5f;
            float w = bx.z - bx.x, h = bx.w - bx.y;
            float4 pc = pr_cxcy[p];
            float g0 = (cx - pc.x) / (pc.z * 0.1f);
            float g1 = (cy - pc.y) / (pc.w * 0.1f);
            float g2 = logf(w / pc.z) * 5.0f;
            float g3 = logf(h / pc.w) * 5.0f;
            float4 pl = plocs[idx];
            lloc = fabsf(pl.x - g0) + fabsf(pl.y - g1) +
                   fabsf(pl.z - g2) + fabsf(pl.w - g3);
        }
    }
    si[tid] = np; s1[tid] = cpos; s2[tid] = lloc;
    __syncthreads();   // also guarantees all shist atomics are visible
    for (int s = 128; s > 0; s >>= 1) {
        if (tid < s) {
            si[tid] += si[tid + s];
            s1[tid] += s1[tid + s];
            s2[tid] += s2[tid + s];
        }
        __syncthreads();
    }
    if (tid == 0) {
        int o = b * NBLK + blockIdx.x;
        npos_part[o] = si[0];
        cpos_part[o] = s1[0];
        loc_part[o] = s2[0];
    }
    // merge per-block histogram into per-image global hist (nonzero bins only)
    for (int i = tid; i < 2048; i += 256) {
        int c = shist[i];
        if (c) atomicAdd(&ghist[b * 2048 + i], c);
    }
}

// ---------------- kernel E: per-image exact top-K sum via 3-level radix select ----------------
__device__ __forceinline__ float block_sum(float v, float* fred, int tid) {
    fred[tid] = v;
    __syncthreads();
    for (int s = 128; s > 0; s >>= 1) {
        if (tid < s) fred[tid] += fred[tid + s];
        __syncthreads();
    }
    float r = fred[0];
    __syncthreads();
    return r;
}

__global__ void k_select(const float* __restrict__ confneg,
                         const int* __restrict__ ghist,
                         const int* __restrict__ npos_part,
                         float* __restrict__ chard) {
    int b = blockIdx.x, tid = threadIdx.x;
    __shared__ int h[2048];
    __shared__ float store[2048];
    __shared__ float fred[256];
    __shared__ int ired[256];
    __shared__ int bc[8];

    ired[tid] = (tid < NBLK) ? npos_part[b * NBLK + tid] : 0;
    __syncthreads();
    for (int s = 128; s > 0; s >>= 1) {
        if (tid < s) ired[tid] += ired[tid + s];
        __syncthreads();
    }
    int npos = ired[0];
    long long Kl = 3LL * npos;
    int K = (Kl > PP) ? PP : (int)Kl;
    if (K == 0) {
        if (tid == 0) chard[b] = 0.0f;
        return;
    }

    // level 1: top 11 bits, histogram prebuilt in k_fused
    for (int i = tid; i < 2048; i += 256) h[i] = ghist[b * 2048 + i];
    __syncthreads();
    if (tid == 0) {
        int acc = 0, b1 = 0, cg = 0;
        for (int i = 2047; i >= 0; --i) {
            acc += h[i];
            if (acc >= K) { b1 = i; cg = acc - h[i]; break; }
        }
        bc[0] = b1; bc[1] = K - cg;     // K1: rank within bucket b1
    }
    __syncthreads();
    int b1 = bc[0], K1 = bc[1];

    // pass A: S_a (sum of strictly-higher buckets) + hist2 of next-10 bits in b1
    for (int i = tid; i < 1024; i += 256) h[i] = 0;
    __syncthreads();
    const float4* cn4 = (const float4*)(confneg + (size_t)b * PP);
    float sa = 0.0f;
    for (int i = tid; i < P4; i += 256) {
        float4 q = cn4[i];
        float vv[4] = {q.x, q.y, q.z, q.w};
        #pragma unroll
        for (int j = 0; j < 4; ++j) {
            unsigned k = __float_as_uint(vv[j]);
            int t11 = (int)(k >> 20);
            if (t11 > b1) sa += vv[j];
            else if (t11 == b1) atomicAdd(&h[(k >> 10) & 1023], 1);
        }
    }
    float Sa = block_sum(sa, fred, tid);
    if (tid == 0) {
        int acc = 0, b2 = 0, cg = 0;
        for (int i = 1023; i >= 0; --i) {
            acc += h[i];
            if (acc >= K1) { b2 = i; cg = acc - h[i]; break; }
        }
        bc[2] = b2; bc[3] = K1 - cg; bc[4] = h[b2];   // K2, count in (b1,b2)
    }
    __syncthreads();
    int b2 = bc[2], K2 = bc[3], h2cnt = bc[4];
    bool collect = (h2cnt <= 2048);

    // pass B: S_b + hist3 of low-10 bits in (b1,b2); collect bucket values
    for (int i = tid; i < 1024; i += 256) h[i] = 0;
    if (tid == 0) bc[5] = 0;
    __syncthreads();
    unsigned top21 = ((unsigned)b1 << 10) | (unsigned)b2;
    float sb = 0.0f;
    for (int i = tid; i < P4; i += 256) {
        float4 q = cn4[i];
        float vv[4] = {q.x, q.y, q.z, q.w};
        #pragma unroll
        for (int j = 0; j < 4; ++j) {
            unsigned k = __float_as_uint(vv[j]);
            if ((int)(k >> 20) == b1) {
                int n10 = (int)((k >> 10) & 1023);
                if (n10 > b2) sb += vv[j];
                else if (n10 == b2) {
                    atomicAdd(&h[k & 1023], 1);
                    if (collect) {
                        int ix = atomicAdd(&bc[5], 1);
                        if (ix < 2048) store[ix] = vv[j];
                    }
                }
            }
        }
    }
    float Sb = block_sum(sb, fred, tid);
    if (tid == 0) {
        int acc = 0, b3 = 0, cg = 0;
        for (int i = 1023; i >= 0; --i) {
            acc += h[i];
            if (acc >= K2) { b3 = i; cg = acc - h[i]; break; }
        }
        bc[6] = b3; bc[7] = K2 - cg;    // K3 = number of ties to take
    }
    __syncthreads();
    int b3 = bc[6], K3 = bc[7];
    unsigned kstar = (top21 << 10) | (unsigned)b3;
    float kval = __uint_as_float(kstar);

    // S_c: sum of values in bucket (b1,b2) strictly above kstar
    float sc = 0.0f;
    if (collect) {
        for (int i = tid; i < h2cnt; i += 256)
            if (__float_as_uint(store[i]) > kstar) sc += store[i];
    } else {
        for (int i = tid; i < P4; i += 256) {
            float4 q = cn4[i];
            float vv[4] = {q.x, q.y, q.z, q.w};
            #pragma unroll
            for (int j = 0; j < 4; ++j) {
                unsigned k = __float_as_uint(vv[j]);
                if ((k >> 10) == top21 && (k & 1023) > (unsigned)b3) sc += vv[j];
            }
        }
    }
    float Sc = block_sum(sc, fred, tid);
    if (tid == 0) chard[b] = Sa + Sb + Sc + (float)K3 * kval;
}

// ---------------- kernel F: final deterministic combine ----------------
__global__ void k_final(const int* __restrict__ npos_part,
                        const float* __restrict__ cpos_part,
                        const float* __restrict__ loc_part,
                        const float* __restrict__ chard,
                        float* __restrict__ out) {
    __shared__ int si[256];
    __shared__ float s1[256], s2[256], s3[256];
    int tn = 0; float tc = 0.0f, tl = 0.0f;
    for (int i = threadIdx.x; i < BB * NBLK; i += 256) {
        tn += npos_part[i];
        tc += cpos_part[i];
        tl += loc_part[i];
    }
    float th = (threadIdx.x < BB) ? chard[threadIdx.x] : 0.0f;
    si[threadIdx.x] = tn; s1[threadIdx.x] = tc; s2[threadIdx.x] = tl; s3[threadIdx.x] = th;
    __syncthreads();
    for (int s = 128; s > 0; s >>= 1) {
        if (threadIdx.x < s) {
            si[threadIdx.x] += si[threadIdx.x + s];
            s1[threadIdx.x] += s1[threadIdx.x + s];
            s2[threadIdx.x] += s2[threadIdx.x + s];
            s3[threadIdx.x] += s3[threadIdx.x + s];
        }
        __syncthreads();
    }
    if (threadIdx.x == 0) {
        float tp = (float)si[0];
        out[0] = (s3[0] + s1[0]) / tp + s2[0] / (tp * 4.0f);
    }
}

extern "C" void kernel_launch(void* const* d_in, const int* in_sizes, int n_in,
                              void* d_out, int out_size, void* d_ws, size_t ws_size,
                              hipStream_t stream) {
    const float4* plocs   = (const float4*)d_in[0];   // (B,P,4)
    const float2* scores  = (const float2*)d_in[1];   // (B,P,2)
    const float4* boxes   = (const float4*)d_in[2];   // (B,M,4)
    const float4* priors  = (const float4*)d_in[3];   // (P,4) cxcywh
    float* out = (float*)d_out;

    char* ws = (char*)d_ws;
    size_t off = 0;
    auto alloc = [&](size_t bytes) -> void* {
        void* p = ws + off;
        off += (bytes + 255) & ~(size_t)255;
        return p;
    };
    float4* pr_xy    = (float4*)alloc((size_t)PP * 16);
    float*  parea    = (float*) alloc((size_t)PP * 4);
    int*    pfeo     = (int*)   alloc((size_t)BB * MM * 4);
    float*  confneg  = (float*) alloc((size_t)BB * PP * 4);
    int*    ghist    = (int*)   alloc((size_t)BB * 2048 * 4);
    int*    npos_p   = (int*)   alloc((size_t)BB * NBLK * 4);
    float*  cpos_p   = (float*) alloc((size_t)BB * NBLK * 4);
    float*  loc_p    = (float*) alloc((size_t)BB * NBLK * 4);
    float*  chard    = (float*) alloc((size_t)BB * 4);
    (void)ws_size; (void)in_sizes; (void)n_in; (void)out_size;

    k_priors<<<dim3(NBLK), 256, 0, stream>>>(priors, pr_xy, parea, ghist);
    k_best_per_object<<<dim3(MM, BB), 256, 0, stream>>>(pr_xy, parea, boxes, pfeo);
    k_fused<<<dim3(NBLK, BB), 256, 0, stream>>>(pr_xy, parea, boxes, pfeo, priors,
                                                plocs, scores, confneg, ghist,
                                                npos_p, cpos_p, loc_p);
    k_select<<<BB, 256, 0, stream>>>(confneg, ghist, npos_p, chard);
    k_final<<<1, 256, 0, stream>>>(npos_p, cpos_p, loc_p, chard, out);
}

// Round 4
// 190.336 us; speedup vs baseline: 4.6351x; 2.0435x over previous
//
#include <hip/hip_runtime.h>
#include <math.h>

// Problem constants (from reference setup_inputs)
#define BB 64
#define MM 50
#define PP 24564
#define CC 2
#define NBLK ((PP + 255) / 256)   // 96 blocks of 256 over priors
#define THRESH 0.2f
#define P4 (PP / 4)               // 6141 float4s, exact

// ---------------- kernel 0: priors cxcy -> xy + area, and zero ghist ----------------
__global__ void k_priors(const float4* __restrict__ pr_cxcy,
                         float4* __restrict__ pr_xy,
                         float* __restrict__ parea,
                         int* __restrict__ ghist) {
    int p = blockIdx.x * 256 + threadIdx.x;
    for (int i = p; i < BB * 2048; i += NBLK * 256) ghist[i] = 0;
    if (p >= PP) return;
    float4 c = pr_cxcy[p];
    float4 xy;
    xy.x = c.x - c.z * 0.5f;
    xy.y = c.y - c.w * 0.5f;
    xy.z = c.x + c.z * 0.5f;
    xy.w = c.y + c.w * 0.5f;
    pr_xy[p] = xy;
    parea[p] = (xy.z - xy.x) * (xy.w - xy.y);
}

__device__ __forceinline__ float iou_fn(float4 a, float area_a, float4 b, float area_b) {
    float lx = fmaxf(a.x, b.x), ly = fmaxf(a.y, b.y);
    float rx = fminf(a.z, b.z), ry = fminf(a.w, b.w);
    float iw = fmaxf(rx - lx, 0.0f), ih = fmaxf(ry - ly, 0.0f);
    float inter = iw * ih;
    return inter / (area_a + area_b - inter);
}

// ---------------- kernel B: per-object best prior (argmax over P) ----------------
__global__ void k_best_per_object(const float4* __restrict__ pr_xy,
                                  const float* __restrict__ parea,
                                  const float4* __restrict__ boxes,
                                  int* __restrict__ pfeo) {
    int m = blockIdx.x, b = blockIdx.y;
    float4 bx = boxes[b * MM + m];
    float ba = (bx.z - bx.x) * (bx.w - bx.y);
    unsigned long long bestkey = 0ull;
    for (int p = threadIdx.x; p < PP; p += 256) {
        float iou = iou_fn(bx, ba, pr_xy[p], parea[p]);
        // iou >= 0 -> float bits monotone as u32; tie -> larger ~p = smaller p wins
        unsigned long long key =
            ((unsigned long long)__float_as_uint(iou) << 32) | (unsigned int)(~p);
        if (key > bestkey) bestkey = key;
    }
    __shared__ unsigned long long sk[256];
    sk[threadIdx.x] = bestkey;
    __syncthreads();
    for (int s = 128; s > 0; s >>= 1) {
        if (threadIdx.x < s) {
            unsigned long long o = sk[threadIdx.x + s];
            if (o > sk[threadIdx.x]) sk[threadIdx.x] = o;
        }
        __syncthreads();
    }
    if (threadIdx.x == 0) pfeo[b * MM + m] = (int)(~(unsigned int)sk[0]);
}

// ---------------- fused kernel: best-per-prior + force + loss terms + LDS-agg hist ----------------
__global__ void k_fused(const float4* __restrict__ pr_xy,
                        const float* __restrict__ parea,
                        const float4* __restrict__ boxes,
                        const int* __restrict__ pfeo,
                        const float4* __restrict__ pr_cxcy,
                        const float4* __restrict__ plocs,
                        const float2* __restrict__ scores,
                        float* __restrict__ confneg,
                        int* __restrict__ ghist,
                        int* __restrict__ npos_part,
                        float* __restrict__ cpos_part,
                        float* __restrict__ loc_part) {
    int b = blockIdx.y;
    int p = blockIdx.x * 256 + threadIdx.x;
    int tid = threadIdx.x;
    __shared__ float4 sbox[MM];
    __shared__ float sarea[MM];
    __shared__ int spfeo[MM];
    __shared__ int shist[2048];
    __shared__ int si[256];
    __shared__ float s1[256], s2[256];
    for (int i = tid; i < 2048; i += 256) shist[i] = 0;
    if (tid < MM) {
        float4 bx = boxes[b * MM + tid];
        sbox[tid] = bx;
        sarea[tid] = (bx.z - bx.x) * (bx.w - bx.y);
        spfeo[tid] = pfeo[b * MM + tid];
    }
    __syncthreads();

    int np = 0;
    float cpos = 0.0f, lloc = 0.0f;
    if (p < PP) {
        float4 pxy = pr_xy[p];
        float pa = parea[p];
        float best = -1.0f;
        int bm = 0;
        for (int m = 0; m < MM; ++m) {
            float iou = iou_fn(sbox[m], sarea[m], pxy, pa);
            if (iou > best) { best = iou; bm = m; }   // strict > : first occurrence wins
        }
        // force-assign: last m wins on duplicate priors (matches sequential scatter)
        for (int m = 0; m < MM; ++m) {
            if (spfeo[m] == p) { bm = m; best = 1.0f; }
        }
        bool pos = (best >= THRESH);
        size_t idx = (size_t)b * PP + p;
        float2 sc = scores[idx];
        float mx = fmaxf(sc.x, sc.y);
        float lse = mx + logf(expf(sc.x - mx) + expf(sc.y - mx));
        float conf = pos ? (lse - sc.y) : (lse - sc.x);   // -logp[label]
        float key = pos ? 0.0f : conf;
        confneg[idx] = key;
        atomicAdd(&shist[__float_as_uint(key) >> 20], 1);
        if (pos) {
            np = 1;
            cpos = conf;
            float4 bx = sbox[bm];
            float cx = (bx.x + bx.z) * 0.5f, cy = (bx.y + bx.w) * 0.5f;
            float w = bx.z - bx.x, h = bx.w - bx.y;
            float4 pc = pr_cxcy[p];
            float g0 = (cx - pc.x) / (pc.z * 0.1f);
            float g1 = (cy - pc.y) / (pc.w * 0.1f);
            float g2 = logf(w / pc.z) * 5.0f;
            float g3 = logf(h / pc.w) * 5.0f;
            float4 pl = plocs[idx];
            lloc = fabsf(pl.x - g0) + fabsf(pl.y - g1) +
                   fabsf(pl.z - g2) + fabsf(pl.w - g3);
        }
    }
    si[tid] = np; s1[tid] = cpos; s2[tid] = lloc;
    __syncthreads();   // also guarantees all shist atomics are visible
    for (int s = 128; s > 0; s >>= 1) {
        if (tid < s) {
            si[tid] += si[tid + s];
            s1[tid] += s1[tid + s];
            s2[tid] += s2[tid + s];
        }
        __syncthreads();
    }
    if (tid == 0) {
        int o = b * NBLK + blockIdx.x;
        npos_part[o] = si[0];
        cpos_part[o] = s1[0];
        loc_part[o] = s2[0];
    }
    // merge per-block histogram into per-image global hist (nonzero bins only)
    for (int i = tid; i < 2048; i += 256) {
        int c = shist[i];
        if (c) atomicAdd(&ghist[b * 2048 + i], c);
    }
}

// ---------------- kernel E: per-image exact top-K sum via 3-level radix select ----------------
__device__ __forceinline__ float block_sum(float v, float* fred, int tid) {
    fred[tid] = v;
    __syncthreads();
    for (int s = 128; s > 0; s >>= 1) {
        if (tid < s) fred[tid] += fred[tid + s];
        __syncthreads();
    }
    float r = fred[0];
    __syncthreads();
    return r;
}

// Parallel: find largest bucket index b* with suffix_count(b*) >= K over NB bins.
// Writes bcast[slot] = b*, bcast[slot+1] = count strictly greater than b*.
template <int NB>
__device__ __forceinline__ void suffix_find(const int* __restrict__ h, int K, int tid,
                                            int* iscr, int* bcast, int slot) {
    const int c = NB / 256;
    const int base = tid * c;
    int tsum = 0;
    #pragma unroll
    for (int i = 0; i < c; ++i) tsum += h[base + i];
    iscr[tid] = tsum;
    __syncthreads();
    int val = tsum;                       // Hillis-Steele inclusive suffix scan
    for (int off = 1; off < 256; off <<= 1) {
        int other = (tid + off < 256) ? iscr[tid + off] : 0;
        __syncthreads();
        val += other;
        iscr[tid] = val;
        __syncthreads();
    }
    int acc = val - tsum;                 // suffix count of bins owned by threads > tid
    int best = -1, cg = 0;
    for (int i = base + c - 1; i >= base; --i) {
        int s = acc + h[i];               // suffix_count(i)
        if (s >= K) { best = i; cg = acc; break; }   // largest qualifying in range
        acc = s;
    }
    iscr[tid] = best;
    __syncthreads();
    for (int s2 = 128; s2 > 0; s2 >>= 1) {
        if (tid < s2) iscr[tid] = max(iscr[tid], iscr[tid + s2]);
        __syncthreads();
    }
    int gbest = iscr[0];
    __syncthreads();
    if (best == gbest && best >= 0) { bcast[slot] = gbest; bcast[slot + 1] = cg; }
    __syncthreads();
}

__global__ void k_select(const float* __restrict__ confneg,
                         const int* __restrict__ ghist,
                         const int* __restrict__ npos_part,
                         float* __restrict__ chard) {
    int b = blockIdx.x, tid = threadIdx.x;
    __shared__ int h[2048];
    __shared__ float store[4096];
    __shared__ float fred[256];
    __shared__ int iscr[256];
    __shared__ int bcast[8];

    // reduce this image's n_pos partials
    iscr[tid] = (tid < NBLK) ? npos_part[b * NBLK + tid] : 0;
    __syncthreads();
    for (int s = 128; s > 0; s >>= 1) {
        if (tid < s) iscr[tid] += iscr[tid + s];
        __syncthreads();
    }
    int npos = iscr[0];
    __syncthreads();
    long long Kl = 3LL * npos;
    int K = (Kl > PP) ? PP : (int)Kl;
    if (K == 0) {
        if (tid == 0) chard[b] = 0.0f;
        return;
    }

    // level 1: top 11 bits, histogram prebuilt in k_fused
    for (int i = tid; i < 2048; i += 256) h[i] = ghist[b * 2048 + i];
    __syncthreads();
    suffix_find<2048>(h, K, tid, iscr, bcast, 0);
    int b1 = bcast[0];
    int K1 = K - bcast[1];
    int h1cnt = h[b1];                     // known BEFORE pass A
    bool docollect = (h1cnt <= 4096);
    __syncthreads();

    // pass A (only global sweep in the common path):
    // S_a = sum of strictly-higher buckets; hist2 of next-10 bits within b1;
    // collect all b1-bucket values into LDS if they fit.
    for (int i = tid; i < 1024; i += 256) h[i] = 0;
    if (tid == 0) bcast[6] = 0;
    __syncthreads();
    const float4* cn4 = (const float4*)(confneg + (size_t)b * PP);
    float sa = 0.0f;
    for (int i = tid; i < P4; i += 256) {
        float4 q = cn4[i];
        float vv[4] = {q.x, q.y, q.z, q.w};
        #pragma unroll
        for (int j = 0; j < 4; ++j) {
            unsigned k = __float_as_uint(vv[j]);
            int t11 = (int)(k >> 20);
            if (t11 > b1) sa += vv[j];
            else if (t11 == b1) {
                atomicAdd(&h[(k >> 10) & 1023], 1);
                if (docollect) {
                    int ix = atomicAdd(&bcast[6], 1);
                    store[ix] = vv[j];
                }
            }
        }
    }
    float Sa = block_sum(sa, fred, tid);
    suffix_find<1024>(h, K1, tid, iscr, bcast, 2);
    int b2 = bcast[2];
    int K2 = K1 - bcast[3];
    unsigned top21 = ((unsigned)b1 << 10) | (unsigned)b2;
    __syncthreads();

    float Sb, Sc;
    int b3, K3;
    if (docollect) {
        // level 3 entirely from LDS store (h1cnt values of bucket b1)
        for (int i = tid; i < 1024; i += 256) h[i] = 0;
        __syncthreads();
        float sb = 0.0f;
        for (int i = tid; i < h1cnt; i += 256) {
            unsigned k = __float_as_uint(store[i]);
            int n10 = (int)((k >> 10) & 1023);
            if (n10 > b2) sb += store[i];
            else if (n10 == b2) atomicAdd(&h[k & 1023], 1);
        }
        Sb = block_sum(sb, fred, tid);
        suffix_find<1024>(h, K2, tid, iscr, bcast, 4);
        b3 = bcast[4];
        K3 = K2 - bcast[5];
        float sc = 0.0f;
        for (int i = tid; i < h1cnt; i += 256) {
            unsigned k = __float_as_uint(store[i]);
            if ((k >> 10) == top21 && (k & 1023) > (unsigned)b3) sc += store[i];
        }
        Sc = block_sum(sc, fred, tid);
    } else {
        // fallback: two more global sweeps
        for (int i = tid; i < 1024; i += 256) h[i] = 0;
        __syncthreads();
        float sb = 0.0f;
        for (int i = tid; i < P4; i += 256) {
            float4 q = cn4[i];
            float vv[4] = {q.x, q.y, q.z, q.w};
            #pragma unroll
            for (int j = 0; j < 4; ++j) {
                unsigned k = __float_as_uint(vv[j]);
                if ((int)(k >> 20) == b1) {
                    int n10 = (int)((k >> 10) & 1023);
                    if (n10 > b2) sb += vv[j];
                    else if (n10 == b2) atomicAdd(&h[k & 1023], 1);
                }
            }
        }
        Sb = block_sum(sb, fred, tid);
        suffix_find<1024>(h, K2, tid, iscr, bcast, 4);
        b3 = bcast[4];
        K3 = K2 - bcast[5];
        float sc = 0.0f;
        for (int i = tid; i < P4; i += 256) {
            float4 q = cn4[i];
            float vv[4] = {q.x, q.y, q.z, q.w};
            #pragma unroll
            for (int j = 0; j < 4; ++j) {
                unsigned k = __float_as_uint(vv[j]);
                if ((k >> 10) == top21 && (k & 1023) > (unsigned)b3) sc += vv[j];
            }
        }
        Sc = block_sum(sc, fred, tid);
    }
    if (tid == 0) {
        unsigned kstar = (top21 << 10) | (unsigned)b3;
        chard[b] = Sa + Sb + Sc + (float)K3 * __uint_as_float(kstar);
    }
}

// ---------------- kernel F: final deterministic combine ----------------
__global__ void k_final(const int* __restrict__ npos_part,
                        const float* __restrict__ cpos_part,
                        const float* __restrict__ loc_part,
                        const float* __restrict__ chard,
                        float* __restrict__ out) {
    __shared__ int si[256];
    __shared__ float s1[256], s2[256], s3[256];
    int tn = 0; float tc = 0.0f, tl = 0.0f;
    for (int i = threadIdx.x; i < BB * NBLK; i += 256) {
        tn += npos_part[i];
        tc += cpos_part[i];
        tl += loc_part[i];
    }
    float th = (threadIdx.x < BB) ? chard[threadIdx.x] : 0.0f;
    si[threadIdx.x] = tn; s1[threadIdx.x] = tc; s2[threadIdx.x] = tl; s3[threadIdx.x] = th;
    __syncthreads();
    for (int s = 128; s > 0; s >>= 1) {
        if (threadIdx.x < s) {
            si[threadIdx.x] += si[threadIdx.x + s];
            s1[threadIdx.x] += s1[threadIdx.x + s];
            s2[threadIdx.x] += s2[threadIdx.x + s];
            s3[threadIdx.x] += s3[threadIdx.x + s];
        }
        __syncthreads();
    }
    if (threadIdx.x == 0) {
        float tp = (float)si[0];
        out[0] = (s3[0] + s1[0]) / tp + s2[0] / (tp * 4.0f);
    }
}

extern "C" void kernel_launch(void* const* d_in, const int* in_sizes, int n_in,
                              void* d_out, int out_size, void* d_ws, size_t ws_size,
                              hipStream_t stream) {
    const float4* plocs   = (const float4*)d_in[0];   // (B,P,4)
    const float2* scores  = (const float2*)d_in[1];   // (B,P,2)
    const float4* boxes   = (const float4*)d_in[2];   // (B,M,4)
    const float4* priors  = (const float4*)d_in[3];   // (P,4) cxcywh
    float* out = (float*)d_out;

    char* ws = (char*)d_ws;
    size_t off = 0;
    auto alloc = [&](size_t bytes) -> void* {
        void* p = ws + off;
        off += (bytes + 255) & ~(size_t)255;
        return p;
    };
    float4* pr_xy    = (float4*)alloc((size_t)PP * 16);
    float*  parea    = (float*) alloc((size_t)PP * 4);
    int*    pfeo     = (int*)   alloc((size_t)BB * MM * 4);
    float*  confneg  = (float*) alloc((size_t)BB * PP * 4);
    int*    ghist    = (int*)   alloc((size_t)BB * 2048 * 4);
    int*    npos_p   = (int*)   alloc((size_t)BB * NBLK * 4);
    float*  cpos_p   = (float*) alloc((size_t)BB * NBLK * 4);
    float*  loc_p    = (float*) alloc((size_t)BB * NBLK * 4);
    float*  chard    = (float*) alloc((size_t)BB * 4);
    (void)ws_size; (void)in_sizes; (void)n_in; (void)out_size;

    k_priors<<<dim3(NBLK), 256, 0, stream>>>(priors, pr_xy, parea, ghist);
    k_best_per_object<<<dim3(MM, BB), 256, 0, stream>>>(pr_xy, parea, boxes, pfeo);
    k_fused<<<dim3(NBLK, BB), 256, 0, stream>>>(pr_xy, parea, boxes, pfeo, priors,
                                                plocs, scores, confneg, ghist,
                                                npos_p, cpos_p, loc_p);
    k_select<<<BB, 256, 0, stream>>>(confneg, ghist, npos_p, chard);
    k_final<<<1, 256, 0, stream>>>(npos_p, cpos_p, loc_p, chard, out);
}

// Round 5
// 160.299 us; speedup vs baseline: 5.5036x; 1.1874x over previous
//
#include <hip/hip_runtime.h>
#include <math.h>

// Problem constants (from reference setup_inputs)
#define BB 64
#define MM 50
#define PP 24564
#define CC 2
#define NBLK ((PP + 255) / 256)   // 96 blocks of 256 over priors
#define THRESH 0.2f
#define P4 (PP / 4)               // 6141 float4s, exact
#define MCH 5                     // objects per block in k_best_per_object
#define MGRID (MM / MCH)          // 10

// ---------------- kernel 0: priors cxcy -> xy + area, and zero ghist ----------------
__global__ void k_priors(const float4* __restrict__ pr_cxcy,
                         float4* __restrict__ pr_xy,
                         float* __restrict__ parea,
                         int* __restrict__ ghist) {
    int p = blockIdx.x * 256 + threadIdx.x;
    for (int i = p; i < BB * 2048; i += NBLK * 256) ghist[i] = 0;
    if (p >= PP) return;
    float4 c = pr_cxcy[p];
    float4 xy;
    xy.x = c.x - c.z * 0.5f;
    xy.y = c.y - c.w * 0.5f;
    xy.z = c.x + c.z * 0.5f;
    xy.w = c.y + c.w * 0.5f;
    pr_xy[p] = xy;
    parea[p] = (xy.z - xy.x) * (xy.w - xy.y);
}

// ---------------- kernel B: per-object best prior, 5 objects/block, division-free ----------------
__global__ void k_best_per_object(const float4* __restrict__ pr_xy,
                                  const float* __restrict__ parea,
                                  const float4* __restrict__ boxes,
                                  int* __restrict__ pfeo) {
    int b = blockIdx.y;
    int m0 = blockIdx.x * MCH;
    int tid = threadIdx.x;
    float4 bx[MCH];
    float ba[MCH];
    #pragma unroll
    for (int j = 0; j < MCH; ++j) {
        bx[j] = boxes[b * MM + m0 + j];
        ba[j] = (bx[j].z - bx[j].x) * (bx[j].w - bx[j].y);
    }
    // running best per object: quotient bi/bd, tie -> smaller p
    float bi[MCH], bd[MCH];
    int bp[MCH];
    #pragma unroll
    for (int j = 0; j < MCH; ++j) { bi[j] = 0.0f; bd[j] = 1.0f; bp[j] = 0; }
    for (int p = tid; p < PP; p += 256) {
        float4 pxy = pr_xy[p];
        float pa = parea[p];
        #pragma unroll
        for (int j = 0; j < MCH; ++j) {
            float lx = fmaxf(bx[j].x, pxy.x), ly = fmaxf(bx[j].y, pxy.y);
            float rx = fminf(bx[j].z, pxy.z), ry = fminf(bx[j].w, pxy.w);
            float iw = fmaxf(rx - lx, 0.0f), ih = fmaxf(ry - ly, 0.0f);
            float inter = iw * ih;
            float den = ba[j] + pa - inter;
            // inter/den > bi/bd  <=>  inter*bd > bi*den   (den,bd > 0)
            float l = inter * bd[j], r = bi[j] * den;
            if (l > r) { bi[j] = inter; bd[j] = den; bp[j] = p; }
            // l == r keeps earlier (smaller) p within this thread
        }
    }
    __shared__ float sI[256], sD[256];
    __shared__ int sP[256];
    for (int j = 0; j < MCH; ++j) {
        sI[tid] = bi[j]; sD[tid] = bd[j]; sP[tid] = bp[j];
        __syncthreads();
        for (int s = 128; s > 0; s >>= 1) {
            if (tid < s) {
                float l = sI[tid + s] * sD[tid], r = sI[tid] * sD[tid + s];
                if (l > r || (l == r && sP[tid + s] < sP[tid])) {
                    sI[tid] = sI[tid + s]; sD[tid] = sD[tid + s]; sP[tid] = sP[tid + s];
                }
            }
            __syncthreads();
        }
        if (tid == 0) pfeo[b * MM + m0 + j] = sP[0];
        __syncthreads();
    }
}

// ---------------- fused kernel: best-per-prior + force + loss terms + LDS-agg hist ----------------
__global__ void k_fused(const float4* __restrict__ pr_xy,
                        const float* __restrict__ parea,
                        const float4* __restrict__ boxes,
                        const int* __restrict__ pfeo,
                        const float4* __restrict__ pr_cxcy,
                        const float4* __restrict__ plocs,
                        const float2* __restrict__ scores,
                        float* __restrict__ confneg,
                        int* __restrict__ ghist,
                        int* __restrict__ npos_part,
                        float* __restrict__ cpos_part,
                        float* __restrict__ loc_part) {
    int b = blockIdx.y;
    int p = blockIdx.x * 256 + threadIdx.x;
    int tid = threadIdx.x;
    __shared__ float4 sbox[MM];
    __shared__ float sarea[MM];
    __shared__ int spfeo[MM];
    __shared__ int shist[2048];
    __shared__ int si[256];
    __shared__ float s1[256], s2[256];
    for (int i = tid; i < 2048; i += 256) shist[i] = 0;
    if (tid < MM) {
        float4 bx = boxes[b * MM + tid];
        sbox[tid] = bx;
        sarea[tid] = (bx.z - bx.x) * (bx.w - bx.y);
        spfeo[tid] = pfeo[b * MM + tid];
    }
    __syncthreads();

    int np = 0;
    float cpos = 0.0f, lloc = 0.0f;
    if (p < PP) {
        float4 pxy = pr_xy[p];
        float pa = parea[p];
        // division-free argmax over m: quotient binter/bdenom, tie -> first m
        float binter = 0.0f, bdenom = 1.0f;
        int bm = 0;
        for (int m = 0; m < MM; ++m) {
            float4 bxm = sbox[m];
            float lx = fmaxf(bxm.x, pxy.x), ly = fmaxf(bxm.y, pxy.y);
            float rx = fminf(bxm.z, pxy.z), ry = fminf(bxm.w, pxy.w);
            float iw = fmaxf(rx - lx, 0.0f), ih = fmaxf(ry - ly, 0.0f);
            float inter = iw * ih;
            float den = sarea[m] + pa - inter;
            float l = inter * bdenom, r = binter * den;
            if (l > r) { binter = inter; bdenom = den; bm = m; }
        }
        float best = binter / bdenom;   // same operands as reference's overlap quotient
        // force-assign: last m wins on duplicate priors (matches sequential scatter)
        for (int m = 0; m < MM; ++m) {
            if (spfeo[m] == p) { bm = m; best = 1.0f; }
        }
        bool pos = (best >= THRESH);
        size_t idx = (size_t)b * PP + p;
        float2 sc = scores[idx];
        float mx = fmaxf(sc.x, sc.y);
        float lse = mx + logf(expf(sc.x - mx) + expf(sc.y - mx));
        float conf = pos ? (lse - sc.y) : (lse - sc.x);   // -logp[label]
        float key = pos ? 0.0f : conf;
        confneg[idx] = key;
        atomicAdd(&shist[__float_as_uint(key) >> 20], 1);
        if (pos) {
            np = 1;
            cpos = conf;
            float4 bx = sbox[bm];
            float cx = (bx.x + bx.z) * 0.5f, cy = (bx.y + bx.w) * 0.5f;
            float w = bx.z - bx.x, h = bx.w - bx.y;
            float4 pc = pr_cxcy[p];
            float g0 = (cx - pc.x) / (pc.z * 0.1f);
            float g1 = (cy - pc.y) / (pc.w * 0.1f);
            float g2 = logf(w / pc.z) * 5.0f;
            float g3 = logf(h / pc.w) * 5.0f;
            float4 pl = plocs[idx];
            lloc = fabsf(pl.x - g0) + fabsf(pl.y - g1) +
                   fabsf(pl.z - g2) + fabsf(pl.w - g3);
        }
    }
    si[tid] = np; s1[tid] = cpos; s2[tid] = lloc;
    __syncthreads();   // also guarantees all shist atomics are visible
    for (int s = 128; s > 0; s >>= 1) {
        if (tid < s) {
            si[tid] += si[tid + s];
            s1[tid] += s1[tid + s];
            s2[tid] += s2[tid + s];
        }
        __syncthreads();
    }
    if (tid == 0) {
        int o = b * NBLK + blockIdx.x;
        npos_part[o] = si[0];
        cpos_part[o] = s1[0];
        loc_part[o] = s2[0];
    }
    // merge per-block histogram into per-image global hist (nonzero bins only)
    for (int i = tid; i < 2048; i += 256) {
        int c = shist[i];
        if (c) atomicAdd(&ghist[b * 2048 + i], c);
    }
}

// ---------------- kernel E: per-image exact top-K sum via 3-level radix select ----------------
__device__ __forceinline__ float block_sum(float v, float* fred, int tid) {
    fred[tid] = v;
    __syncthreads();
    for (int s = 128; s > 0; s >>= 1) {
        if (tid < s) fred[tid] += fred[tid + s];
        __syncthreads();
    }
    float r = fred[0];
    __syncthreads();
    return r;
}

// Parallel: find largest bucket index b* with suffix_count(b*) >= K over NB bins.
// Writes bcast[slot] = b*, bcast[slot+1] = count strictly greater than b*.
template <int NB>
__device__ __forceinline__ void suffix_find(const int* __restrict__ h, int K, int tid,
                                            int* iscr, int* bcast, int slot) {
    const int c = NB / 256;
    const int base = tid * c;
    int tsum = 0;
    #pragma unroll
    for (int i = 0; i < c; ++i) tsum += h[base + i];
    iscr[tid] = tsum;
    __syncthreads();
    int val = tsum;                       // Hillis-Steele inclusive suffix scan
    for (int off = 1; off < 256; off <<= 1) {
        int other = (tid + off < 256) ? iscr[tid + off] : 0;
        __syncthreads();
        val += other;
        iscr[tid] = val;
        __syncthreads();
    }
    int acc = val - tsum;                 // suffix count of bins owned by threads > tid
    int best = -1, cg = 0;
    for (int i = base + c - 1; i >= base; --i) {
        int s = acc + h[i];               // suffix_count(i)
        if (s >= K) { best = i; cg = acc; break; }   // largest qualifying in range
        acc = s;
    }
    iscr[tid] = best;
    __syncthreads();
    for (int s2 = 128; s2 > 0; s2 >>= 1) {
        if (tid < s2) iscr[tid] = max(iscr[tid], iscr[tid + s2]);
        __syncthreads();
    }
    int gbest = iscr[0];
    __syncthreads();
    if (best == gbest && best >= 0) { bcast[slot] = gbest; bcast[slot + 1] = cg; }
    __syncthreads();
}

__global__ void k_select(const float* __restrict__ confneg,
                         const int* __restrict__ ghist,
                         const int* __restrict__ npos_part,
                         float* __restrict__ chard) {
    int b = blockIdx.x, tid = threadIdx.x;
    __shared__ int h[2048];
    __shared__ float store[4096];
    __shared__ float fred[256];
    __shared__ int iscr[256];
    __shared__ int bcast[8];

    // reduce this image's n_pos partials
    iscr[tid] = (tid < NBLK) ? npos_part[b * NBLK + tid] : 0;
    __syncthreads();
    for (int s = 128; s > 0; s >>= 1) {
        if (tid < s) iscr[tid] += iscr[tid + s];
        __syncthreads();
    }
    int npos = iscr[0];
    __syncthreads();
    long long Kl = 3LL * npos;
    int K = (Kl > PP) ? PP : (int)Kl;
    if (K == 0) {
        if (tid == 0) chard[b] = 0.0f;
        return;
    }

    // level 1: top 11 bits, histogram prebuilt in k_fused
    for (int i = tid; i < 2048; i += 256) h[i] = ghist[b * 2048 + i];
    __syncthreads();
    suffix_find<2048>(h, K, tid, iscr, bcast, 0);
    int b1 = bcast[0];
    int K1 = K - bcast[1];
    int h1cnt = h[b1];                     // known BEFORE pass A
    bool docollect = (h1cnt <= 4096);
    __syncthreads();

    // pass A (only global sweep in the common path)
    for (int i = tid; i < 1024; i += 256) h[i] = 0;
    if (tid == 0) bcast[6] = 0;
    __syncthreads();
    const float4* cn4 = (const float4*)(confneg + (size_t)b * PP);
    float sa = 0.0f;
    for (int i = tid; i < P4; i += 256) {
        float4 q = cn4[i];
        float vv[4] = {q.x, q.y, q.z, q.w};
        #pragma unroll
        for (int j = 0; j < 4; ++j) {
            unsigned k = __float_as_uint(vv[j]);
            int t11 = (int)(k >> 20);
            if (t11 > b1) sa += vv[j];
            else if (t11 == b1) {
                atomicAdd(&h[(k >> 10) & 1023], 1);
                if (docollect) {
                    int ix = atomicAdd(&bcast[6], 1);
                    store[ix] = vv[j];
                }
            }
        }
    }
    float Sa = block_sum(sa, fred, tid);
    suffix_find<1024>(h, K1, tid, iscr, bcast, 2);
    int b2 = bcast[2];
    int K2 = K1 - bcast[3];
    unsigned top21 = ((unsigned)b1 << 10) | (unsigned)b2;
    __syncthreads();

    float Sb, Sc;
    int b3, K3;
    if (docollect) {
        for (int i = tid; i < 1024; i += 256) h[i] = 0;
        __syncthreads();
        float sb = 0.0f;
        for (int i = tid; i < h1cnt; i += 256) {
            unsigned k = __float_as_uint(store[i]);
            int n10 = (int)((k >> 10) & 1023);
            if (n10 > b2) sb += store[i];
            else if (n10 == b2) atomicAdd(&h[k & 1023], 1);
        }
        Sb = block_sum(sb, fred, tid);
        suffix_find<1024>(h, K2, tid, iscr, bcast, 4);
        b3 = bcast[4];
        K3 = K2 - bcast[5];
        float sc = 0.0f;
        for (int i = tid; i < h1cnt; i += 256) {
            unsigned k = __float_as_uint(store[i]);
            if ((k >> 10) == top21 && (k & 1023) > (unsigned)b3) sc += store[i];
        }
        Sc = block_sum(sc, fred, tid);
    } else {
        for (int i = tid; i < 1024; i += 256) h[i] = 0;
        __syncthreads();
        float sb = 0.0f;
        for (int i = tid; i < P4; i += 256) {
            float4 q = cn4[i];
            float vv[4] = {q.x, q.y, q.z, q.w};
            #pragma unroll
            for (int j = 0; j < 4; ++j) {
                unsigned k = __float_as_uint(vv[j]);
                if ((int)(k >> 20) == b1) {
                    int n10 = (int)((k >> 10) & 1023);
                    if (n10 > b2) sb += vv[j];
                    else if (n10 == b2) atomicAdd(&h[k & 1023], 1);
                }
            }
        }
        Sb = block_sum(sb, fred, tid);
        suffix_find<1024>(h, K2, tid, iscr, bcast, 4);
        b3 = bcast[4];
        K3 = K2 - bcast[5];
        float sc = 0.0f;
        for (int i = tid; i < P4; i += 256) {
            float4 q = cn4[i];
            float vv[4] = {q.x, q.y, q.z, q.w};
            #pragma unroll
            for (int j = 0; j < 4; ++j) {
                unsigned k = __float_as_uint(vv[j]);
                if ((k >> 10) == top21 && (k & 1023) > (unsigned)b3) sc += vv[j];
            }
        }
        Sc = block_sum(sc, fred, tid);
    }
    if (tid == 0) {
        unsigned kstar = (top21 << 10) | (unsigned)b3;
        chard[b] = Sa + Sb + Sc + (float)K3 * __uint_as_float(kstar);
    }
}

// ---------------- kernel F: final deterministic combine ----------------
__global__ void k_final(const int* __restrict__ npos_part,
                        const float* __restrict__ cpos_part,
                        const float* __restrict__ loc_part,
                        const float* __restrict__ chard,
                        float* __restrict__ out) {
    __shared__ int si[256];
    __shared__ float s1[256], s2[256], s3[256];
    int tn = 0; float tc = 0.0f, tl = 0.0f;
    for (int i = threadIdx.x; i < BB * NBLK; i += 256) {
        tn += npos_part[i];
        tc += cpos_part[i];
        tl += loc_part[i];
    }
    float th = (threadIdx.x < BB) ? chard[threadIdx.x] : 0.0f;
    si[threadIdx.x] = tn; s1[threadIdx.x] = tc; s2[threadIdx.x] = tl; s3[threadIdx.x] = th;
    __syncthreads();
    for (int s = 128; s > 0; s >>= 1) {
        if (threadIdx.x < s) {
            si[threadIdx.x] += si[threadIdx.x + s];
            s1[threadIdx.x] += s1[threadIdx.x + s];
            s2[threadIdx.x] += s2[threadIdx.x + s];
            s3[threadIdx.x] += s3[threadIdx.x + s];
        }
        __syncthreads();
    }
    if (threadIdx.x == 0) {
        float tp = (float)si[0];
        out[0] = (s3[0] + s1[0]) / tp + s2[0] / (tp * 4.0f);
    }
}

extern "C" void kernel_launch(void* const* d_in, const int* in_sizes, int n_in,
                              void* d_out, int out_size, void* d_ws, size_t ws_size,
                              hipStream_t stream) {
    const float4* plocs   = (const float4*)d_in[0];   // (B,P,4)
    const float2* scores  = (const float2*)d_in[1];   // (B,P,2)
    const float4* boxes   = (const float4*)d_in[2];   // (B,M,4)
    const float4* priors  = (const float4*)d_in[3];   // (P,4) cxcywh
    float* out = (float*)d_out;

    char* ws = (char*)d_ws;
    size_t off = 0;
    auto alloc = [&](size_t bytes) -> void* {
        void* p = ws + off;
        off += (bytes + 255) & ~(size_t)255;
        return p;
    };
    float4* pr_xy    = (float4*)alloc((size_t)PP * 16);
    float*  parea    = (float*) alloc((size_t)PP * 4);
    int*    pfeo     = (int*)   alloc((size_t)BB * MM * 4);
    float*  confneg  = (float*) alloc((size_t)BB * PP * 4);
    int*    ghist    = (int*)   alloc((size_t)BB * 2048 * 4);
    int*    npos_p   = (int*)   alloc((size_t)BB * NBLK * 4);
    float*  cpos_p   = (float*) alloc((size_t)BB * NBLK * 4);
    float*  loc_p    = (float*) alloc((size_t)BB * NBLK * 4);
    float*  chard    = (float*) alloc((size_t)BB * 4);
    (void)ws_size; (void)in_sizes; (void)n_in; (void)out_size;

    k_priors<<<dim3(NBLK), 256, 0, stream>>>(priors, pr_xy, parea, ghist);
    k_best_per_object<<<dim3(MGRID, BB), 256, 0, stream>>>(pr_xy, parea, boxes, pfeo);
    k_fused<<<dim3(NBLK, BB), 256, 0, stream>>>(pr_xy, parea, boxes, pfeo, priors,
                                                plocs, scores, confneg, ghist,
                                                npos_p, cpos_p, loc_p);
    k_select<<<BB, 256, 0, stream>>>(confneg, ghist, npos_p, chard);
    k_final<<<1, 256, 0, stream>>>(npos_p, cpos_p, loc_p, chard, out);
}

// Round 6
// 159.050 us; speedup vs baseline: 5.5468x; 1.0079x over previous
//
#include <hip/hip_runtime.h>
#include <math.h>

// Problem constants (from reference setup_inputs)
#define BB 64
#define MM 50
#define PP 24564
#define CC 2
#define NBLK ((PP + 255) / 256)   // 96 blocks of 256 over priors
#define THRESH 0.2f
#define P4 (PP / 4)               // 6141 float4s, exact
#define MCH 10                    // objects per block in k_best_per_object
#define MGRID (MM / MCH)          // 5
#define NC 8                      // P-chunks in k_best_per_object
#define PCHUNK ((PP + NC - 1) / NC)   // 3071

// ---------------- kernel 0: priors cxcy -> xy + area; zero ghist + pfeo64 ----------------
__global__ void k_priors(const float4* __restrict__ pr_cxcy,
                         float4* __restrict__ pr_xy,
                         float* __restrict__ parea,
                         int* __restrict__ ghist,
                         unsigned long long* __restrict__ pfeo64) {
    int p = blockIdx.x * 256 + threadIdx.x;
    for (int i = p; i < BB * 2048; i += NBLK * 256) ghist[i] = 0;
    if (p < BB * MM) pfeo64[p] = 0ull;
    if (p >= PP) return;
    float4 c = pr_cxcy[p];
    float4 xy;
    xy.x = c.x - c.z * 0.5f;
    xy.y = c.y - c.w * 0.5f;
    xy.z = c.x + c.z * 0.5f;
    xy.w = c.y + c.w * 0.5f;
    pr_xy[p] = xy;
    parea[p] = (xy.z - xy.x) * (xy.w - xy.y);
}

// ---------------- kernel B: per-object best prior ----------------
// grid (MGRID, NC, BB): 10 objects/block, 1/8 of priors/block, barrier-free.
// Cross-chunk merge via global atomicMax on key = (f32(quotient)<<32) | ~p
// -> compares rounded quotients (reference semantics), tie -> smaller p
//    (first-occurrence argmax). Deterministic: max over unique keys.
__global__ void k_best_per_object(const float4* __restrict__ pr_xy,
                                  const float* __restrict__ parea,
                                  const float4* __restrict__ boxes,
                                  unsigned long long* __restrict__ pfeo64) {
    int b = blockIdx.z;
    int m0 = blockIdx.x * MCH;
    int c = blockIdx.y;
    int tid = threadIdx.x;
    int pstart = c * PCHUNK;
    int pend = min(pstart + PCHUNK, PP);
    float4 bx[MCH];
    float ba[MCH];
    #pragma unroll
    for (int j = 0; j < MCH; ++j) {
        bx[j] = boxes[b * MM + m0 + j];
        ba[j] = (bx[j].z - bx[j].x) * (bx[j].w - bx[j].y);
    }
    // running best per object: exact rational quotient bi/bd, tie -> smaller p
    float bi[MCH], bd[MCH];
    int bp[MCH];
    #pragma unroll
    for (int j = 0; j < MCH; ++j) { bi[j] = 0.0f; bd[j] = 1.0f; bp[j] = 0; }
    for (int p = pstart + tid; p < pend; p += 256) {
        float4 pxy = pr_xy[p];
        float pa = parea[p];
        #pragma unroll
        for (int j = 0; j < MCH; ++j) {
            float lx = fmaxf(bx[j].x, pxy.x), ly = fmaxf(bx[j].y, pxy.y);
            float rx = fminf(bx[j].z, pxy.z), ry = fminf(bx[j].w, pxy.w);
            float iw = fmaxf(rx - lx, 0.0f), ih = fmaxf(ry - ly, 0.0f);
            float inter = iw * ih;
            float den = ba[j] + pa - inter;
            // inter/den > bi/bd  <=>  inter*bd > bi*den   (den,bd > 0)
            float l = inter * bd[j], r = bi[j] * den;
            if (l > r) { bi[j] = inter; bd[j] = den; bp[j] = p; }
            // l == r keeps earlier (smaller) p within this thread
        }
    }
    // wave-level butterfly reduce (symmetric comparator -> all lanes converge)
    #pragma unroll
    for (int j = 0; j < MCH; ++j) {
        float I = bi[j], D = bd[j];
        int P_ = bp[j];
        #pragma unroll
        for (int off = 32; off > 0; off >>= 1) {
            float oI = __shfl_xor(I, off);
            float oD = __shfl_xor(D, off);
            int oP = __shfl_xor(P_, off);
            float l = oI * D, r = I * oD;
            if (l > r || (l == r && oP < P_)) { I = oI; D = oD; P_ = oP; }
        }
        if ((tid & 63) == 0) {
            float q = I / D;   // rounded f32 quotient, reference's compare key
            unsigned long long key =
                ((unsigned long long)__float_as_uint(q) << 32) | (unsigned int)(~P_);
            atomicMax(&pfeo64[b * MM + m0 + j], key);
        }
    }
}

// ---------------- fused kernel: best-per-prior + force + loss terms + LDS-agg hist ----------------
__global__ void k_fused(const float4* __restrict__ pr_xy,
                        const float* __restrict__ parea,
                        const float4* __restrict__ boxes,
                        const unsigned long long* __restrict__ pfeo64,
                        const float4* __restrict__ pr_cxcy,
                        const float4* __restrict__ plocs,
                        const float2* __restrict__ scores,
                        float* __restrict__ confneg,
                        int* __restrict__ ghist,
                        int* __restrict__ npos_part,
                        float* __restrict__ cpos_part,
                        float* __restrict__ loc_part) {
    int b = blockIdx.y;
    int p = blockIdx.x * 256 + threadIdx.x;
    int tid = threadIdx.x;
    __shared__ float4 sbox[MM];
    __shared__ float sarea[MM];
    __shared__ int spfeo[MM];
    __shared__ int shist[2048];
    __shared__ int si[256];
    __shared__ float s1[256], s2[256];
    for (int i = tid; i < 2048; i += 256) shist[i] = 0;
    if (tid < MM) {
        float4 bx = boxes[b * MM + tid];
        sbox[tid] = bx;
        sarea[tid] = (bx.z - bx.x) * (bx.w - bx.y);
        spfeo[tid] = (int)(~(unsigned int)(pfeo64[b * MM + tid] & 0xFFFFFFFFull));
    }
    __syncthreads();

    int np = 0;
    float cpos = 0.0f, lloc = 0.0f;
    if (p < PP) {
        float4 pxy = pr_xy[p];
        float pa = parea[p];
        // division-free argmax over m: quotient binter/bdenom, tie -> first m
        float binter = 0.0f, bdenom = 1.0f;
        int bm = 0;
        for (int m = 0; m < MM; ++m) {
            float4 bxm = sbox[m];
            float lx = fmaxf(bxm.x, pxy.x), ly = fmaxf(bxm.y, pxy.y);
            float rx = fminf(bxm.z, pxy.z), ry = fminf(bxm.w, pxy.w);
            float iw = fmaxf(rx - lx, 0.0f), ih = fmaxf(ry - ly, 0.0f);
            float inter = iw * ih;
            float den = sarea[m] + pa - inter;
            float l = inter * bdenom, r = binter * den;
            if (l > r) { binter = inter; bdenom = den; bm = m; }
        }
        float best = binter / bdenom;   // same operands as reference's overlap quotient
        // force-assign: last m wins on duplicate priors (matches sequential scatter)
        for (int m = 0; m < MM; ++m) {
            if (spfeo[m] == p) { bm = m; best = 1.0f; }
        }
        bool pos = (best >= THRESH);
        size_t idx = (size_t)b * PP + p;
        float2 sc = scores[idx];
        float mx = fmaxf(sc.x, sc.y);
        float lse = mx + logf(expf(sc.x - mx) + expf(sc.y - mx));
        float conf = pos ? (lse - sc.y) : (lse - sc.x);   // -logp[label]
        float key = pos ? 0.0f : conf;
        confneg[idx] = key;
        atomicAdd(&shist[__float_as_uint(key) >> 20], 1);
        if (pos) {
            np = 1;
            cpos = conf;
            float4 bx = sbox[bm];
            float cx = (bx.x + bx.z) * 0.5f, cy = (bx.y + bx.w) * 0.5f;
            float w = bx.z - bx.x, h = bx.w - bx.y;
            float4 pc = pr_cxcy[p];
            float g0 = (cx - pc.x) / (pc.z * 0.1f);
            float g1 = (cy - pc.y) / (pc.w * 0.1f);
            float g2 = logf(w / pc.z) * 5.0f;
            float g3 = logf(h / pc.w) * 5.0f;
            float4 pl = plocs[idx];
            lloc = fabsf(pl.x - g0) + fabsf(pl.y - g1) +
                   fabsf(pl.z - g2) + fabsf(pl.w - g3);
        }
    }
    si[tid] = np; s1[tid] = cpos; s2[tid] = lloc;
    __syncthreads();   // also guarantees all shist atomics are visible
    for (int s = 128; s > 0; s >>= 1) {
        if (tid < s) {
            si[tid] += si[tid + s];
            s1[tid] += s1[tid + s];
            s2[tid] += s2[tid + s];
        }
        __syncthreads();
    }
    if (tid == 0) {
        int o = b * NBLK + blockIdx.x;
        npos_part[o] = si[0];
        cpos_part[o] = s1[0];
        loc_part[o] = s2[0];
    }
    // merge per-block histogram into per-image global hist (nonzero bins only)
    for (int i = tid; i < 2048; i += 256) {
        int c = shist[i];
        if (c) atomicAdd(&ghist[b * 2048 + i], c);
    }
}

// ---------------- kernel E: per-image exact top-K sum via 3-level radix select ----------------
__device__ __forceinline__ float block_sum(float v, float* fred, int tid) {
    fred[tid] = v;
    __syncthreads();
    for (int s = 128; s > 0; s >>= 1) {
        if (tid < s) fred[tid] += fred[tid + s];
        __syncthreads();
    }
    float r = fred[0];
    __syncthreads();
    return r;
}

// Parallel: find largest bucket index b* with suffix_count(b*) >= K over NB bins.
// Writes bcast[slot] = b*, bcast[slot+1] = count strictly greater than b*.
template <int NB>
__device__ __forceinline__ void suffix_find(const int* __restrict__ h, int K, int tid,
                                            int* iscr, int* bcast, int slot) {
    const int c = NB / 256;
    const int base = tid * c;
    int tsum = 0;
    #pragma unroll
    for (int i = 0; i < c; ++i) tsum += h[base + i];
    iscr[tid] = tsum;
    __syncthreads();
    int val = tsum;                       // Hillis-Steele inclusive suffix scan
    for (int off = 1; off < 256; off <<= 1) {
        int other = (tid + off < 256) ? iscr[tid + off] : 0;
        __syncthreads();
        val += other;
        iscr[tid] = val;
        __syncthreads();
    }
    int acc = val - tsum;                 // suffix count of bins owned by threads > tid
    int best = -1, cg = 0;
    for (int i = base + c - 1; i >= base; --i) {
        int s = acc + h[i];               // suffix_count(i)
        if (s >= K) { best = i; cg = acc; break; }   // largest qualifying in range
        acc = s;
    }
    iscr[tid] = best;
    __syncthreads();
    for (int s2 = 128; s2 > 0; s2 >>= 1) {
        if (tid < s2) iscr[tid] = max(iscr[tid], iscr[tid + s2]);
        __syncthreads();
    }
    int gbest = iscr[0];
    __syncthreads();
    if (best == gbest && best >= 0) { bcast[slot] = gbest; bcast[slot + 1] = cg; }
    __syncthreads();
}

__global__ void k_select(const float* __restrict__ confneg,
                         const int* __restrict__ ghist,
                         const int* __restrict__ npos_part,
                         float* __restrict__ chard) {
    int b = blockIdx.x, tid = threadIdx.x;
    __shared__ int h[2048];
    __shared__ float store[4096];
    __shared__ float fred[256];
    __shared__ int iscr[256];
    __shared__ int bcast[8];

    // reduce this image's n_pos partials
    iscr[tid] = (tid < NBLK) ? npos_part[b * NBLK + tid] : 0;
    __syncthreads();
    for (int s = 128; s > 0; s >>= 1) {
        if (tid < s) iscr[tid] += iscr[tid + s];
        __syncthreads();
    }
    int npos = iscr[0];
    __syncthreads();
    long long Kl = 3LL * npos;
    int K = (Kl > PP) ? PP : (int)Kl;
    if (K == 0) {
        if (tid == 0) chard[b] = 0.0f;
        return;
    }

    // level 1: top 11 bits, histogram prebuilt in k_fused
    for (int i = tid; i < 2048; i += 256) h[i] = ghist[b * 2048 + i];
    __syncthreads();
    suffix_find<2048>(h, K, tid, iscr, bcast, 0);
    int b1 = bcast[0];
    int K1 = K - bcast[1];
    int h1cnt = h[b1];                     // known BEFORE pass A
    bool docollect = (h1cnt <= 4096);
    __syncthreads();

    // pass A (only global sweep in the common path)
    for (int i = tid; i < 1024; i += 256) h[i] = 0;
    if (tid == 0) bcast[6] = 0;
    __syncthreads();
    const float4* cn4 = (const float4*)(confneg + (size_t)b * PP);
    float sa = 0.0f;
    for (int i = tid; i < P4; i += 256) {
        float4 q = cn4[i];
        float vv[4] = {q.x, q.y, q.z, q.w};
        #pragma unroll
        for (int j = 0; j < 4; ++j) {
            unsigned k = __float_as_uint(vv[j]);
            int t11 = (int)(k >> 20);
            if (t11 > b1) sa += vv[j];
            else if (t11 == b1) {
                atomicAdd(&h[(k >> 10) & 1023], 1);
                if (docollect) {
                    int ix = atomicAdd(&bcast[6], 1);
                    store[ix] = vv[j];
                }
            }
        }
    }
    float Sa = block_sum(sa, fred, tid);
    suffix_find<1024>(h, K1, tid, iscr, bcast, 2);
    int b2 = bcast[2];
    int K2 = K1 - bcast[3];
    unsigned top21 = ((unsigned)b1 << 10) | (unsigned)b2;
    __syncthreads();

    float Sb, Sc;
    int b3, K3;
    if (docollect) {
        for (int i = tid; i < 1024; i += 256) h[i] = 0;
        __syncthreads();
        float sb = 0.0f;
        for (int i = tid; i < h1cnt; i += 256) {
            unsigned k = __float_as_uint(store[i]);
            int n10 = (int)((k >> 10) & 1023);
            if (n10 > b2) sb += store[i];
            else if (n10 == b2) atomicAdd(&h[k & 1023], 1);
        }
        Sb = block_sum(sb, fred, tid);
        suffix_find<1024>(h, K2, tid, iscr, bcast, 4);
        b3 = bcast[4];
        K3 = K2 - bcast[5];
        float sc = 0.0f;
        for (int i = tid; i < h1cnt; i += 256) {
            unsigned k = __float_as_uint(store[i]);
            if ((k >> 10) == top21 && (k & 1023) > (unsigned)b3) sc += store[i];
        }
        Sc = block_sum(sc, fred, tid);
    } else {
        for (int i = tid; i < 1024; i += 256) h[i] = 0;
        __syncthreads();
        float sb = 0.0f;
        for (int i = tid; i < P4; i += 256) {
            float4 q = cn4[i];
            float vv[4] = {q.x, q.y, q.z, q.w};
            #pragma unroll
            for (int j = 0; j < 4; ++j) {
                unsigned k = __float_as_uint(vv[j]);
                if ((int)(k >> 20) == b1) {
                    int n10 = (int)((k >> 10) & 1023);
                    if (n10 > b2) sb += vv[j];
                    else if (n10 == b2) atomicAdd(&h[k & 1023], 1);
                }
            }
        }
        Sb = block_sum(sb, fred, tid);
        suffix_find<1024>(h, K2, tid, iscr, bcast, 4);
        b3 = bcast[4];
        K3 = K2 - bcast[5];
        float sc = 0.0f;
        for (int i = tid; i < P4; i += 256) {
            float4 q = cn4[i];
            float vv[4] = {q.x, q.y, q.z, q.w};
            #pragma unroll
            for (int j = 0; j < 4; ++j) {
                unsigned k = __float_as_uint(vv[j]);
                if ((k >> 10) == top21 && (k & 1023) > (unsigned)b3) sc += vv[j];
            }
        }
        Sc = block_sum(sc, fred, tid);
    }
    if (tid == 0) {
        unsigned kstar = (top21 << 10) | (unsigned)b3;
        chard[b] = Sa + Sb + Sc + (float)K3 * __uint_as_float(kstar);
    }
}

// ---------------- kernel F: final deterministic combine ----------------
__global__ void k_final(const int* __restrict__ npos_part,
                        const float* __restrict__ cpos_part,
                        const float* __restrict__ loc_part,
                        const float* __restrict__ chard,
                        float* __restrict__ out) {
    __shared__ int si[256];
    __shared__ float s1[256], s2[256], s3[256];
    int tn = 0; float tc = 0.0f, tl = 0.0f;
    for (int i = threadIdx.x; i < BB * NBLK; i += 256) {
        tn += npos_part[i];
        tc += cpos_part[i];
        tl += loc_part[i];
    }
    float th = (threadIdx.x < BB) ? chard[threadIdx.x] : 0.0f;
    si[threadIdx.x] = tn; s1[threadIdx.x] = tc; s2[threadIdx.x] = tl; s3[threadIdx.x] = th;
    __syncthreads();
    for (int s = 128; s > 0; s >>= 1) {
        if (threadIdx.x < s) {
            si[threadIdx.x] += si[threadIdx.x + s];
            s1[threadIdx.x] += s1[threadIdx.x + s];
            s2[threadIdx.x] += s2[threadIdx.x + s];
            s3[threadIdx.x] += s3[threadIdx.x + s];
        }
        __syncthreads();
    }
    if (threadIdx.x == 0) {
        float tp = (float)si[0];
        out[0] = (s3[0] + s1[0]) / tp + s2[0] / (tp * 4.0f);
    }
}

extern "C" void kernel_launch(void* const* d_in, const int* in_sizes, int n_in,
                              void* d_out, int out_size, void* d_ws, size_t ws_size,
                              hipStream_t stream) {
    const float4* plocs   = (const float4*)d_in[0];   // (B,P,4)
    const float2* scores  = (const float2*)d_in[1];   // (B,P,2)
    const float4* boxes   = (const float4*)d_in[2];   // (B,M,4)
    const float4* priors  = (const float4*)d_in[3];   // (P,4) cxcywh
    float* out = (float*)d_out;

    char* ws = (char*)d_ws;
    size_t off = 0;
    auto alloc = [&](size_t bytes) -> void* {
        void* p = ws + off;
        off += (bytes + 255) & ~(size_t)255;
        return p;
    };
    float4*             pr_xy   = (float4*)alloc((size_t)PP * 16);
    float*              parea   = (float*) alloc((size_t)PP * 4);
    unsigned long long* pfeo64  = (unsigned long long*)alloc((size_t)BB * MM * 8);
    float*              confneg = (float*) alloc((size_t)BB * PP * 4);
    int*                ghist   = (int*)   alloc((size_t)BB * 2048 * 4);
    int*                npos_p  = (int*)   alloc((size_t)BB * NBLK * 4);
    float*              cpos_p  = (float*) alloc((size_t)BB * NBLK * 4);
    float*              loc_p   = (float*) alloc((size_t)BB * NBLK * 4);
    float*              chard   = (float*) alloc((size_t)BB * 4);
    (void)ws_size; (void)in_sizes; (void)n_in; (void)out_size;

    k_priors<<<dim3(NBLK), 256, 0, stream>>>(priors, pr_xy, parea, ghist, pfeo64);
    k_best_per_object<<<dim3(MGRID, NC, BB), 256, 0, stream>>>(pr_xy, parea, boxes, pfeo64);
    k_fused<<<dim3(NBLK, BB), 256, 0, stream>>>(pr_xy, parea, boxes, pfeo64, priors,
                                                plocs, scores, confneg, ghist,
                                                npos_p, cpos_p, loc_p);
    k_select<<<BB, 256, 0, stream>>>(confneg, ghist, npos_p, chard);
    k_final<<<1, 256, 0, stream>>>(npos_p, cpos_p, loc_p, chard, out);
}